// Round 6
// baseline (445.860 us; speedup 1.0000x reference)
//
#include <hip/hip_runtime.h>
#include <hip/hip_bf16.h>

// Downsample: ternary-quantized conv3x3 stride2 pad1, NCHW.
// x:(32,384,64,64) f32, w:(384,384,3,3) f32, bias:(384,) f32 -> out:(32,384,32,32) f32
// Implicit GEMM: M=32768 (n,oh,ow), N=384 (o), K=3456 ((kh,kw,c)), bf16 MFMA.
// Round 9: maximize residency AND keep cover.
//   - lW SINGLE buffer (16 KiB) + lX double (32 KiB) = 48 KiB -> 3 blocks/CU,
//     all 768 blocks co-resident (zero streaming tail; R5's 17.6% occupancy
//     showed the 80KiB/2-per-CU config ran 1/3 of the time at 1 block/CU).
//   - X(t+1) issued at TOP of step t (full-step cover > HBM ~900cy).
//   - W(t+1) issued after a mid-step lgkmcnt(0)+barrier (lW buffer freed once
//     all waves sampled their reads); covered by the MFMA cluster; W is L2-hot.
//   - End-step edge: vmcnt(0)+barrier -- a COVERED drain (everything
//     outstanding was issued >=1 phase earlier and is needed next step).
//   - Staging swizzle / ds_read pattern / MFMA order byte-identical to the
//     verified R0/R5 mappings -> bitwise-same accumulation.
// Deterministic: no atomics anywhere.

#define CIN   384
#define HIN   64
#define WIN   64
#define OHW   32
#define KDIM  3456          // 9*384
#define NWELT 1327104       // 384*384*9
#define MDIM  32768         // 32*32*32
#define NT    54            // K-steps of 64; t = khkw*6 + cc  (k = t*64)

using bf16 = __hip_bfloat16;
typedef __attribute__((ext_vector_type(8))) short short8;   // MFMA A/B frag (8 bf16)
typedef __attribute__((ext_vector_type(4))) float floatx4;  // MFMA C/D frag
typedef __attribute__((ext_vector_type(2))) unsigned short ushort2v;

#define AS1 __attribute__((address_space(1)))
#define AS3 __attribute__((address_space(3)))
#define DMA16(g, l) __builtin_amdgcn_global_load_lds((const AS1 void*)(g), (AS3 void*)(l), 16, 0, 0)

// edges: wait + raw barrier + sched fence.
#define EDGE_L() do { \
    asm volatile("s_waitcnt lgkmcnt(0)" ::: "memory"); \
    __builtin_amdgcn_s_barrier(); \
    __builtin_amdgcn_sched_barrier(0); \
} while (0)
#define EDGE_V0() do { \
    asm volatile("s_waitcnt vmcnt(0)" ::: "memory"); \
    __builtin_amdgcn_s_barrier(); \
    __builtin_amdgcn_sched_barrier(0); \
} while (0)

// ws layout (floats): [0]=alpha, [1]=thr, [2..64)=62 partials; f[16..20) is
// REUSED as a 16B zero region (written by absum_final AFTER consuming partials).
// bytes [256, 256+100663296): x_nhwc bf16 [32][64][64][384]
// bytes [256+100663296, +2654208): Wq bf16 [384][3456] (k=(kh*3+kw)*384+c)
#define NPART  62
#define ZG_F   16
#define XN_OFF 256
#define WQ_OFF (256 + 100663296)

// ---- Stage 1: fixed-slot partial sums of |w| (no atomics -> deterministic) ----
__global__ void absum_part(const float* __restrict__ w, float* __restrict__ ws) {
    const float4* w4 = (const float4*)w;
    float s = 0.f;
    for (int i = blockIdx.x * 256 + threadIdx.x; i < NWELT / 4; i += NPART * 256) {
        float4 v = w4[i];
        s += fabsf(v.x) + fabsf(v.y) + fabsf(v.z) + fabsf(v.w);
    }
    for (int off = 32; off; off >>= 1) s += __shfl_down(s, off, 64);
    __shared__ float red[4];
    if ((threadIdx.x & 63) == 0) red[threadIdx.x >> 6] = s;
    __syncthreads();
    if (threadIdx.x == 0) ws[2 + blockIdx.x] = red[0] + red[1] + red[2] + red[3];
}

// ---- Stage 2: fixed-order final reduction; also zero the DMA guard region ----
__global__ void absum_final(float* __restrict__ ws) {
    if (threadIdx.x == 0) {
        float s = 0.f;
        for (int i = 0; i < NPART; ++i) s += ws[2 + i];
        float alpha = s * (1.0f / NWELT);
        ws[0] = alpha;
        ws[1] = 1e-3f * alpha;
        ws[ZG_F + 0] = 0.f; ws[ZG_F + 1] = 0.f;   // 16B zero guard (partials dead now)
        ws[ZG_F + 2] = 0.f; ws[ZG_F + 3] = 0.f;
    }
}

// ---- Ternary quantize, output-indexed (coalesced 2B writes; reads L2/L3-hot) ----
__global__ void quant_kernel(const float* __restrict__ w, const float* __restrict__ ws,
                             bf16* __restrict__ wq) {
    int j = blockIdx.x * 256 + threadIdx.x;   // j = o*3456 + (kh*3+kw)*384 + c
    if (j >= NWELT) return;
    float thr = ws[1];
    int o = j / KDIM;
    int rmd = j - o * KDIM;
    int khkw = rmd / 384;
    int c = rmd - khkw * 384;
    float v = w[((o * 384 + c) * 9) + khkw];
    float q = (v > thr) ? 1.f : ((v < -thr) ? -1.f : 0.f);
    wq[j] = __float2bfloat16(q);
}

// ---- NCHW f32 -> NHWC bf16. Block: 64c x 64w for one (n,h). grid=(2048, 6). ----
__global__ void nhwc_kernel(const float* __restrict__ x, bf16* __restrict__ xn) {
    int nh = blockIdx.x;
    int n = nh >> 6, h = nh & 63;
    int c0 = blockIdx.y * 64;
    __shared__ bf16 tile[64][66];   // stride 66: column reads ~conflict-free (33c banks)
    const float* src = x + ((n * CIN + c0) * HIN + h) * WIN;  // c-row stride 4096 floats
    for (int i = 0; i < 4; ++i) {
        int s = threadIdx.x + i * 256;     // [0,1024): 64c x 16 float4
        int cl = s >> 4, w4 = (s & 15) * 4;
        float4 v = *(const float4*)(src + cl * 4096 + w4);
        bf16 t0[2], t1[2];
        t0[0] = __float2bfloat16(v.x); t0[1] = __float2bfloat16(v.y);
        t1[0] = __float2bfloat16(v.z); t1[1] = __float2bfloat16(v.w);
        *(ushort2v*)&tile[cl][w4]     = *(ushort2v*)t0;   // 4B aligned
        *(ushort2v*)&tile[cl][w4 + 2] = *(ushort2v*)t1;
    }
    __syncthreads();
    bf16* dst = xn + ((size_t)(n * HIN + h) * WIN) * CIN + c0;
    for (int i = 0; i < 2; ++i) {
        int q = threadIdx.x + i * 256;     // [0,512): 64w x 8 c-octets
        int wc = q >> 3, c8 = (q & 7) * 8;
        bf16 tmp[8];
        #pragma unroll
        for (int j = 0; j < 8; ++j) tmp[j] = tile[c8 + j][wc];
        *(short8*)(dst + (size_t)wc * CIN + c8) = *(short8*)tmp;
    }
}

// ---- GEMM: D[o][m] = sum_k Wq[o][k] * X[m][k]. A=Wq, B=X. ----
// BM=128 (m), BN=128 (o), BK=64. 4 waves, each 64x64 (4x4 frags of 16x16x32).
// LDS layout (per buffer, 128 rows x 64 k-elements, unpadded 128B rows):
//   slot(r, oct) at bytes r*128 + oct*16 holds global octet (oct ^ (r&7)) of row r.
// DMA coverage: call (wv,i) covers slots (wv*4+i)*64 + lane; lane's global octet
//   g = (lane&7) ^ (lane>>3), row r = (wv*4+i)*8 + (lane>>3).
// ds_read side: slot = (ks*4 + quad) ^ (lane&7) -> measured conflict-free.
// Step t:
//   1. issue 4 X(t+1) -> lX[(t+1)&1]  (freed at t-1's end edge; full-step cover)
//   2. ds_read all frags of W(t), X(t)
//   3. EDGE_L: lgkmcnt(0)+barrier  (all waves sampled lW -> safe to overwrite)
//   4. issue 4 W(t+1) -> lW  (covered by the MFMA cluster; wq is L2-hot)
//   5. MFMA 2ks x 4x4 (register-only)
//   6. EDGE_V0: vmcnt(0)+barrier  (X(t+1)+W(t+1) landed; both had cover)
#define BM  128
#define BN  128

__global__ __launch_bounds__(256, 3) void conv_gemm(const bf16* __restrict__ xn,
                                                    const bf16* __restrict__ wq,
                                                    const float* __restrict__ ws,
                                                    const float* __restrict__ bias,
                                                    float* __restrict__ out,
                                                    const bf16* __restrict__ zg) {
    __shared__ __align__(16) bf16 lW[BN * 64];       // 16 KiB (single)
    __shared__ __align__(16) bf16 lX[2][BM * 64];    // 32 KiB (total 48 -> 3/CU)
    const int m_base = blockIdx.x * BM;              // 256 m-tiles
    const int o_base = blockIdx.y * BN;              // 3 o-tiles
    const int tid = threadIdx.x;
    const int lane = tid & 63;
    const int wv = tid >> 6;                         // 0..3
    const int wo = (wv & 1) * 64;
    const int wm = (wv >> 1) * 64;
    const int g = (lane & 7) ^ (lane >> 3);          // pre-swizzled global octet

    // ---- staging descriptors (verified layout) ----
    const bf16* pw[4];
    const bf16* pxn[4];
    int oh2[4], ow2[4], wLoff[4], xLoff[4];
    #pragma unroll
    for (int i = 0; i < 4; ++i) {
        int rr = (wv * 4 + i) * 8;                   // row-group base [0,128)
        wLoff[i] = rr * 64;
        xLoff[i] = rr * 64;
        pw[i] = wq + (size_t)(o_base + rr + (lane >> 3)) * KDIM + g * 8;
        int m = m_base + rr + (lane >> 3);
        int n = m >> 10, oh = (m >> 5) & 31, ow = m & 31;
        pxn[i] = xn + (size_t)n * (HIN * WIN * CIN) + g * 8;
        oh2[i] = 2 * oh - 1;
        ow2[i] = 2 * ow - 1;
    }

    const int l15 = lane & 15, quad = lane >> 4, l7 = lane & 7;

    floatx4 acc[4][4];
    #pragma unroll
    for (int i = 0; i < 4; ++i)
        #pragma unroll
        for (int j = 0; j < 4; ++j)
            acc[i][j] = (floatx4){0.f, 0.f, 0.f, 0.f};

    // ---- prologue: X(0)->lX[0], W(0)->lW; covered drain before t=0 ----
    {
        #pragma unroll
        for (int i = 0; i < 4; ++i) {                // X(0): khkw=0 (kh=kw=0), cc=0
            int ih = oh2[i], iw = ow2[i];
            const bf16* p = (ih >= 0 && iw >= 0) ? pxn[i] + (ih * WIN + iw) * CIN : zg;
            DMA16(p, &lX[0][xLoff[i]]);
        }
        #pragma unroll
        for (int i = 0; i < 4; ++i)                  // W(0)
            DMA16(pw[i], &lW[wLoff[i]]);
        EDGE_V0();   // enter t=0 with 0 outstanding
    }

    for (int t = 0; t < NT - 1; ++t) {               // t = 0..52
        const bf16* lXc = lX[t & 1];
        bf16* lXn = lX[(t + 1) & 1];
        const int kW = (t + 1) * 64;                 // W k-offset for step t+1 (linear)
        const int s1 = t + 1;                        // X staging step
        const int khkw1 = s1 / 6, cc1 = s1 - khkw1 * 6;
        const int kh1 = khkw1 / 3, kw1 = khkw1 - kh1 * 3;

        // ---- 1. issue X(t+1): earliest point -> full-step cover ----
        #pragma unroll
        for (int i = 0; i < 4; ++i) {
            int ih = oh2[i] + kh1, iw = ow2[i] + kw1;
            bool valid = (ih >= 0) & (iw >= 0);
            const bf16* p = valid ? pxn[i] + (ih * WIN + iw) * CIN + cc1 * 64 : zg;
            DMA16(p, lXn + xLoff[i]);
        }

        // ---- 2. frag reads, both ks (verified conflict-free pattern) ----
        short8 af[2][4], bfr[2][4];
        #pragma unroll
        for (int ks = 0; ks < 2; ++ks) {
            const int oct = ((ks * 4 + quad) ^ l7) * 8;
            #pragma unroll
            for (int i = 0; i < 4; ++i)
                af[ks][i] = *(const short8*)(lW + (wo + i * 16 + l15) * 64 + oct);
            #pragma unroll
            for (int j = 0; j < 4; ++j)
                bfr[ks][j] = *(const short8*)(lXc + (wm + j * 16 + l15) * 64 + oct);
        }

        // ---- 3. lW sampled by all waves -> free for overwrite ----
        EDGE_L();

        // ---- 4. issue W(t+1) into lW (cover = MFMA cluster; L2-hot) ----
        #pragma unroll
        for (int i = 0; i < 4; ++i)
            DMA16(pw[i] + kW, lW + wLoff[i]);

        // ---- 5. MFMA: 2 ks x 4x4 (order identical to R0 -> bitwise-same acc) ----
        __builtin_amdgcn_s_setprio(1);
        #pragma unroll
        for (int ks = 0; ks < 2; ++ks)
            #pragma unroll
            for (int i = 0; i < 4; ++i)
                #pragma unroll
                for (int j = 0; j < 4; ++j)
                    acc[i][j] = __builtin_amdgcn_mfma_f32_16x16x32_bf16(
                        af[ks][i], bfr[ks][j], acc[i][j], 0, 0, 0);
        __builtin_amdgcn_s_setprio(0);

        // ---- 6. X(t+1)+W(t+1) landed (both covered); swap ----
        EDGE_V0();
    }

    // ---- peeled tail (t = 53): everything resident; no staging, no barrier ----
    {
        const bf16* lXc = lX[53 & 1];
        short8 af[2][4], bfr[2][4];
        #pragma unroll
        for (int ks = 0; ks < 2; ++ks) {
            const int oct = ((ks * 4 + quad) ^ l7) * 8;
            #pragma unroll
            for (int i = 0; i < 4; ++i)
                af[ks][i] = *(const short8*)(lW + (wo + i * 16 + l15) * 64 + oct);
            #pragma unroll
            for (int j = 0; j < 4; ++j)
                bfr[ks][j] = *(const short8*)(lXc + (wm + j * 16 + l15) * 64 + oct);
        }
        __builtin_amdgcn_s_setprio(1);
        #pragma unroll
        for (int ks = 0; ks < 2; ++ks)
            #pragma unroll
            for (int i = 0; i < 4; ++i)
                #pragma unroll
                for (int j = 0; j < 4; ++j)
                    acc[i][j] = __builtin_amdgcn_mfma_f32_16x16x32_bf16(
                        af[ks][i], bfr[ks][j], acc[i][j], 0, 0, 0);
        __builtin_amdgcn_s_setprio(0);
    }

    // ---- epilogue: D row=(lane>>4)*4+reg = o, col=lane&15 = m -> coalesced along ow ----
    float alpha = ws[0];
    #pragma unroll
    for (int i = 0; i < 4; ++i) {
        #pragma unroll
        for (int j = 0; j < 4; ++j) {
            int mm = m_base + wm + j * 16 + l15;
            int n = mm >> 10, oh = (mm >> 5) & 31, ow = mm & 31;
            #pragma unroll
            for (int r = 0; r < 4; ++r) {
                int o = o_base + wo + i * 16 + quad * 4 + r;
                out[((n * 384 + o) * OHW + oh) * OHW + ow] = alpha * acc[i][j][r] + bias[o];
            }
        }
    }
}

extern "C" void kernel_launch(void* const* d_in, const int* in_sizes, int n_in,
                              void* d_out, int out_size, void* d_ws, size_t ws_size,
                              hipStream_t stream) {
    (void)in_sizes; (void)n_in; (void)out_size; (void)ws_size;
    const float* x    = (const float*)d_in[0];
    const float* w    = (const float*)d_in[1];
    const float* bias = (const float*)d_in[2];
    float* out = (float*)d_out;
    float* wsf = (float*)d_ws;
    bf16* xn = (bf16*)((char*)d_ws + XN_OFF);
    bf16* wq = (bf16*)((char*)d_ws + WQ_OFF);
    const bf16* zg = (const bf16*)(wsf + ZG_F);

    absum_part<<<NPART, 256, 0, stream>>>(w, wsf);
    absum_final<<<1, 64, 0, stream>>>(wsf);
    quant_kernel<<<(NWELT + 255) / 256, 256, 0, stream>>>(w, wsf, wq);
    nhwc_kernel<<<dim3(2048, 6), 256, 0, stream>>>(x, xn);
    conv_gemm<<<dim3(MDIM / BM, 384 / BN), 256, 0, stream>>>(xn, wq, wsf, bias, out, zg);
}

// Round 7
// 442.885 us; speedup vs baseline: 1.0067x; 1.0067x over previous
//
#include <hip/hip_runtime.h>
#include <hip/hip_bf16.h>

// Downsample: ternary-quantized conv3x3 stride2 pad1, NCHW.
// x:(32,384,64,64) f32, w:(384,384,3,3) f32, bias:(384,) f32 -> out:(32,384,32,32) f32
// Implicit GEMM: M=32768 (n,oh,ow), N=384 (o), K=3456 ((kh,kw,c)), bf16 MFMA.
// Round 10: R1's 4-phase FENCED schedule (best measured conv, <=117us) with
// one targeted fix: lX triple-buffered, X(t+2) staged at P3/P4 (4-5 phase
// cover vs R1's 1.5) and W-A1(t+1) staging moved to P2 so the single counted
// wait V(2) at P4 retires exactly {X(t+1)x2, W(t+1)x6}. Edges at P1/P2/P3
// keep R1's lockstep phase structure (measured better than fence-free R4-R6).
// Phase bodies / read mappings / MFMA order / epilogue byte-identical to R1.
// Deterministic: no atomics anywhere.

#define CIN   384
#define HIN   64
#define WIN   64
#define OHW   32
#define KDIM  3456          // 9*384
#define NWELT 1327104       // 384*384*9
#define MDIM  32768         // 32*32*32
#define NT    54            // K-steps of 64; t = khkw*6 + cc  (k = t*64)

using bf16 = __hip_bfloat16;
typedef __attribute__((ext_vector_type(8))) short short8;   // MFMA A/B frag (8 bf16)
typedef __attribute__((ext_vector_type(4))) float floatx4;  // MFMA C/D frag
typedef __attribute__((ext_vector_type(2))) unsigned short ushort2v;

#define AS1 __attribute__((address_space(1)))
#define AS3 __attribute__((address_space(3)))
#define DMA16(g, l) __builtin_amdgcn_global_load_lds((const AS1 void*)(g), (AS3 void*)(l), 16, 0, 0)

// phase edge: counted vmem wait + raw barrier + hard scheduling fence.
#define EDGE_V(N) do { \
    asm volatile("s_waitcnt vmcnt(" #N ")" ::: "memory"); \
    __builtin_amdgcn_s_barrier(); \
    __builtin_amdgcn_sched_barrier(0); \
} while (0)

// ws layout (floats): [0]=alpha, [1]=thr, [2..64)=62 partials; f[16..20) is
// REUSED as a 16B zero region (written by absum_final AFTER consuming partials).
// bytes [256, 256+100663296): x_nhwc bf16 [32][64][64][384]
// bytes [256+100663296, +2654208): Wq bf16 [384][3456] (k=(kh*3+kw)*384+c)
#define NPART  62
#define ZG_F   16
#define XN_OFF 256
#define WQ_OFF (256 + 100663296)

// ---- Stage 1: fixed-slot partial sums of |w| (no atomics -> deterministic) ----
__global__ void absum_part(const float* __restrict__ w, float* __restrict__ ws) {
    const float4* w4 = (const float4*)w;
    float s = 0.f;
    for (int i = blockIdx.x * 256 + threadIdx.x; i < NWELT / 4; i += NPART * 256) {
        float4 v = w4[i];
        s += fabsf(v.x) + fabsf(v.y) + fabsf(v.z) + fabsf(v.w);
    }
    for (int off = 32; off; off >>= 1) s += __shfl_down(s, off, 64);
    __shared__ float red[4];
    if ((threadIdx.x & 63) == 0) red[threadIdx.x >> 6] = s;
    __syncthreads();
    if (threadIdx.x == 0) ws[2 + blockIdx.x] = red[0] + red[1] + red[2] + red[3];
}

// ---- Stage 2: fixed-order final reduction; also zero the DMA guard region ----
__global__ void absum_final(float* __restrict__ ws) {
    if (threadIdx.x == 0) {
        float s = 0.f;
        for (int i = 0; i < NPART; ++i) s += ws[2 + i];
        float alpha = s * (1.0f / NWELT);
        ws[0] = alpha;
        ws[1] = 1e-3f * alpha;
        ws[ZG_F + 0] = 0.f; ws[ZG_F + 1] = 0.f;   // 16B zero guard (partials dead now)
        ws[ZG_F + 2] = 0.f; ws[ZG_F + 3] = 0.f;
    }
}

// ---- Ternary quantize, output-indexed (coalesced 2B writes; reads L2/L3-hot) ----
__global__ void quant_kernel(const float* __restrict__ w, const float* __restrict__ ws,
                             bf16* __restrict__ wq) {
    int j = blockIdx.x * 256 + threadIdx.x;   // j = o*3456 + (kh*3+kw)*384 + c
    if (j >= NWELT) return;
    float thr = ws[1];
    int o = j / KDIM;
    int rmd = j - o * KDIM;
    int khkw = rmd / 384;
    int c = rmd - khkw * 384;
    float v = w[((o * 384 + c) * 9) + khkw];
    float q = (v > thr) ? 1.f : ((v < -thr) ? -1.f : 0.f);
    wq[j] = __float2bfloat16(q);
}

// ---- NCHW f32 -> NHWC bf16. Block: 64c x 64w for one (n,h). grid=(2048, 6). ----
__global__ void nhwc_kernel(const float* __restrict__ x, bf16* __restrict__ xn) {
    int nh = blockIdx.x;
    int n = nh >> 6, h = nh & 63;
    int c0 = blockIdx.y * 64;
    __shared__ bf16 tile[64][66];   // stride 66: column reads ~conflict-free (33c banks)
    const float* src = x + ((n * CIN + c0) * HIN + h) * WIN;  // c-row stride 4096 floats
    for (int i = 0; i < 4; ++i) {
        int s = threadIdx.x + i * 256;     // [0,1024): 64c x 16 float4
        int cl = s >> 4, w4 = (s & 15) * 4;
        float4 v = *(const float4*)(src + cl * 4096 + w4);
        bf16 t0[2], t1[2];
        t0[0] = __float2bfloat16(v.x); t0[1] = __float2bfloat16(v.y);
        t1[0] = __float2bfloat16(v.z); t1[1] = __float2bfloat16(v.w);
        *(ushort2v*)&tile[cl][w4]     = *(ushort2v*)t0;   // 4B aligned
        *(ushort2v*)&tile[cl][w4 + 2] = *(ushort2v*)t1;
    }
    __syncthreads();
    bf16* dst = xn + ((size_t)(n * HIN + h) * WIN) * CIN + c0;
    for (int i = 0; i < 2; ++i) {
        int q = threadIdx.x + i * 256;     // [0,512): 64w x 8 c-octets
        int wc = q >> 3, c8 = (q & 7) * 8;
        bf16 tmp[8];
        #pragma unroll
        for (int j = 0; j < 8; ++j) tmp[j] = tile[c8 + j][wc];
        *(short8*)(dst + (size_t)wc * CIN + c8) = *(short8*)tmp;
    }
}

// ---- GEMM: D[o][m] = sum_k Wq[o][k] * X[m][k]. A=Wq (384 rows), B=X (128 rows). ----
// Halves: A0=o[0,192) A1=o[192,384); B0=m[0,64) B1=m[64,128).
// Wave wv: io=wv&3 (o-pos, x48/half), im=wv>>2 (m-pos, x32/half).
// Phase consumption: P1(A0,B0) P2(A0,B1) P3(A1,B1) P4(A1,B0-from-regs).
// Staging (issue order is the FIFO): P1: 3 W-A0(t+1); P2: 3 W-A1(t+1);
//                                    P3: 1 X0(t+2);  P4: 1 X1(t+2).
// Ledger (per wave): enter t with [X0(t+1),X1(t+1)]; P1 +3 -> V(5) (no-op);
// P2 +3 -> V(8) (no-op); P3 +1 -> V(9) (no-op); P4 +1 -> V(2) retires exactly
// {X(t+1)x2, W(t+1)x6} (all of t+1's reads) and leaves [X(t+2)x2].
// Cover: X 4-5 phases (~1.2 steps, HBM-safe); W 2-3 phases (L2-hot, safe).
// Buffers: lW dbuf (writes go to lW[(t+1)&1] != read buf), lX tribuf (writes
// to lX[(t+2)%3] != lX[t%3]); ds_reads complete before their phase's MFMA and
// >=2 barriers precede any overwrite -> no WAR. MFMA order identical to R1.
// LDS row (64 k-elems, 128B, unpadded): slot(r,oct)=r*128+(oct^(r&7))*16;
// DMA dest linear (wave-uniform base + lane*16), global src pre-swizzled via
// g=(lane&7)^(lane>>3); ds_read folds to oct=(ks*4+quad)^(lane&7) -> conflict-free.
#define BM  128

__global__ __launch_bounds__(512, 2) void conv_gemm(const bf16* __restrict__ xn,
                                                    const bf16* __restrict__ wq,
                                                    const float* __restrict__ ws,
                                                    const float* __restrict__ bias,
                                                    float* __restrict__ out,
                                                    const bf16* __restrict__ zg) {
    __shared__ __align__(16) bf16 lW[2][384 * 64];   // 96 KiB
    __shared__ __align__(16) bf16 lX[3][128 * 64];   // 48 KiB (total 144 KiB)
    const int m_base = blockIdx.x * BM;              // 256 blocks
    const int tid = threadIdx.x;
    const int lane = tid & 63;
    const int wv = tid >> 6;          // 0..7
    const int io = wv & 3;            // o wave-position (x48 per half)
    const int im = wv >> 2;           // m wave-position (x32 per half)
    const int g = (lane & 7) ^ (lane >> 3);          // pre-swizzled global octet

    // ---- W staging descriptors (verified R1 layout) ----
    const bf16* pw[2][3];
    int wLoff[2][3];
    #pragma unroll
    for (int h = 0; h < 2; ++h)
        #pragma unroll
        for (int j = 0; j < 3; ++j) {
            int rr = h * 192 + wv * 24 + j * 8;
            pw[h][j] = wq + (size_t)(rr + (lane >> 3)) * KDIM + g * 8;
            wLoff[h][j] = rr * 64;
        }
    // ---- X staging descriptors (verified R1 layout) ----
    const bf16* pxn[2];
    int oh2[2], ow2[2], xLoff[2];
    #pragma unroll
    for (int h = 0; h < 2; ++h) {
        int rr = h * 64 + wv * 8;
        int m = m_base + rr + (lane >> 3);
        int n = m >> 10, oh = (m >> 5) & 31, ow = m & 31;
        pxn[h] = xn + (size_t)n * (HIN * WIN * CIN) + g * 8;
        oh2[h] = 2 * oh - 1;
        ow2[h] = 2 * ow - 1;
        xLoff[h] = rr * 64;
    }

    // ---- ds_read offsets (element units; verified R1) ----
    const int l15 = lane & 15, quad = lane >> 4, l7 = lane & 7;
    const int octA = (quad ^ l7) * 8;         // ks=0 slot
    const int octB = ((4 + quad) ^ l7) * 8;   // ks=1 slot
    int aoff[2][3], boff[2][2];
    #pragma unroll
    for (int h = 0; h < 2; ++h)
        #pragma unroll
        for (int fo = 0; fo < 3; ++fo)
            aoff[h][fo] = (h * 192 + io * 48 + fo * 16 + l15) * 64;
    #pragma unroll
    for (int h = 0; h < 2; ++h)
        #pragma unroll
        for (int fm = 0; fm < 2; ++fm)
            boff[h][fm] = (h * 64 + im * 32 + fm * 16 + l15) * 64;

    floatx4 acc[6][4];
    #pragma unroll
    for (int i = 0; i < 6; ++i)
        #pragma unroll
        for (int j = 0; j < 4; ++j)
            acc[i][j] = (floatx4){0.f, 0.f, 0.f, 0.f};

    // ---- prologue: X(0)->lX[0], W(0)->lW[0], X(1)->lX[1]; EDGE_V(2) ----
    {
        #pragma unroll
        for (int h = 0; h < 2; ++h) {                 // X(0): khkw=0 (kh=kw=0), cc=0
            int ih = oh2[h], iw = ow2[h];
            const bf16* p = (ih >= 0 && iw >= 0) ? pxn[h] + (ih * WIN + iw) * CIN : zg;
            DMA16(p, &lX[0][xLoff[h]]);
        }
        #pragma unroll
        for (int h = 0; h < 2; ++h)                   // W(0)
            #pragma unroll
            for (int j = 0; j < 3; ++j) DMA16(pw[h][j], &lW[0][wLoff[h][j]]);
        #pragma unroll
        for (int h = 0; h < 2; ++h) {                 // X(1): khkw=0, cc=1
            int ih = oh2[h], iw = ow2[h];
            const bf16* p = (ih >= 0 && iw >= 0) ? pxn[h] + (ih * WIN + iw) * CIN + 64 : zg;
            DMA16(p, &lX[1][xLoff[h]]);
        }
        EDGE_V(2);   // X(0)+W(0) landed; [X(1)x2] in flight -> invariant
    }

    short8 af[2][3], bfl[2][2], bfh[2][2];

    for (int t = 0; t < NT - 1; ++t) {               // t = 0..52
        const bf16* lWc = lW[t & 1];
        const bf16* lXc = lX[t % 3];
        bf16* lWn = lW[(t + 1) & 1];
        bf16* lXn2 = lX[(t + 2) % 3];
        const int kW = (t + 1) * 64;                 // W k-offset for step t+1 (linear)
        const int s2 = t + 2;                        // X staging step
        const int kk2 = s2 / 6, cs2 = s2 - kk2 * 6;
        const int kh2 = kk2 / 3, kw2 = kk2 - kh2 * 3;
        const bf16* pxs[2];
        #pragma unroll
        for (int h = 0; h < 2; ++h) {
            int ih = oh2[h] + kh2, iw = ow2[h] + kw2;
            bool valid = (ih >= 0) & (iw >= 0) & (s2 < NT);
            pxs[h] = valid ? pxn[h] + (ih * WIN + iw) * CIN + cs2 * 64 : zg;
        }

        // ---- P1: read af(A0)+bfl(B0); stage 3 W-A0(t+1); MFMA q00 ----
        #pragma unroll
        for (int fo = 0; fo < 3; ++fo) {
            af[0][fo] = *(const short8*)(lWc + aoff[0][fo] + octA);
            af[1][fo] = *(const short8*)(lWc + aoff[0][fo] + octB);
        }
        #pragma unroll
        for (int fm = 0; fm < 2; ++fm) {
            bfl[0][fm] = *(const short8*)(lXc + boff[0][fm] + octA);
            bfl[1][fm] = *(const short8*)(lXc + boff[0][fm] + octB);
        }
        #pragma unroll
        for (int j = 0; j < 3; ++j) DMA16(pw[0][j] + kW, lWn + wLoff[0][j]);
        EDGE_V(5);
        __builtin_amdgcn_s_setprio(1);
        #pragma unroll
        for (int ks = 0; ks < 2; ++ks)
            #pragma unroll
            for (int fo = 0; fo < 3; ++fo)
                #pragma unroll
                for (int fm = 0; fm < 2; ++fm)
                    acc[fo][fm] = __builtin_amdgcn_mfma_f32_16x16x32_bf16(
                        af[ks][fo], bfl[ks][fm], acc[fo][fm], 0, 0, 0);
        __builtin_amdgcn_s_setprio(0);

        // ---- P2: read bfh(B1); stage 3 W-A1(t+1); MFMA q01 ----
        #pragma unroll
        for (int fm = 0; fm < 2; ++fm) {
            bfh[0][fm] = *(const short8*)(lXc + boff[1][fm] + octA);
            bfh[1][fm] = *(const short8*)(lXc + boff[1][fm] + octB);
        }
        #pragma unroll
        for (int j = 0; j < 3; ++j) DMA16(pw[1][j] + kW, lWn + wLoff[1][j]);
        EDGE_V(8);
        __builtin_amdgcn_s_setprio(1);
        #pragma unroll
        for (int ks = 0; ks < 2; ++ks)
            #pragma unroll
            for (int fo = 0; fo < 3; ++fo)
                #pragma unroll
                for (int fm = 0; fm < 2; ++fm)
                    acc[fo][2 + fm] = __builtin_amdgcn_mfma_f32_16x16x32_bf16(
                        af[ks][fo], bfh[ks][fm], acc[fo][2 + fm], 0, 0, 0);
        __builtin_amdgcn_s_setprio(0);

        // ---- P3: read af(A1) (overwrite); stage X0(t+2); MFMA q11 ----
        #pragma unroll
        for (int fo = 0; fo < 3; ++fo) {
            af[0][fo] = *(const short8*)(lWc + aoff[1][fo] + octA);
            af[1][fo] = *(const short8*)(lWc + aoff[1][fo] + octB);
        }
        DMA16(pxs[0], lXn2 + xLoff[0]);
        EDGE_V(9);
        __builtin_amdgcn_s_setprio(1);
        #pragma unroll
        for (int ks = 0; ks < 2; ++ks)
            #pragma unroll
            for (int fo = 0; fo < 3; ++fo)
                #pragma unroll
                for (int fm = 0; fm < 2; ++fm)
                    acc[3 + fo][2 + fm] = __builtin_amdgcn_mfma_f32_16x16x32_bf16(
                        af[ks][fo], bfh[ks][fm], acc[3 + fo][2 + fm], 0, 0, 0);
        __builtin_amdgcn_s_setprio(0);

        // ---- P4: stage X1(t+2); EDGE V(2) retires {X(t+1),W(t+1)}; MFMA q10 ----
        DMA16(pxs[1], lXn2 + xLoff[1]);
        EDGE_V(2);
        __builtin_amdgcn_s_setprio(1);
        #pragma unroll
        for (int ks = 0; ks < 2; ++ks)
            #pragma unroll
            for (int fo = 0; fo < 3; ++fo)
                #pragma unroll
                for (int fm = 0; fm < 2; ++fm)
                    acc[3 + fo][fm] = __builtin_amdgcn_mfma_f32_16x16x32_bf16(
                        af[ks][fo], bfl[ks][fm], acc[3 + fo][fm], 0, 0, 0);
        __builtin_amdgcn_s_setprio(0);
    }

    // ---- peeled tail (t = 53): everything landed at t=52's P4 edge ----
    {
        const bf16* lWc = lW[1];
        const bf16* lXc = lX[53 % 3];    // lX[2]
        // P1
        #pragma unroll
        for (int fo = 0; fo < 3; ++fo) {
            af[0][fo] = *(const short8*)(lWc + aoff[0][fo] + octA);
            af[1][fo] = *(const short8*)(lWc + aoff[0][fo] + octB);
        }
        #pragma unroll
        for (int fm = 0; fm < 2; ++fm) {
            bfl[0][fm] = *(const short8*)(lXc + boff[0][fm] + octA);
            bfl[1][fm] = *(const short8*)(lXc + boff[0][fm] + octB);
        }
        __builtin_amdgcn_s_setprio(1);
        #pragma unroll
        for (int ks = 0; ks < 2; ++ks)
            #pragma unroll
            for (int fo = 0; fo < 3; ++fo)
                #pragma unroll
                for (int fm = 0; fm < 2; ++fm)
                    acc[fo][fm] = __builtin_amdgcn_mfma_f32_16x16x32_bf16(
                        af[ks][fo], bfl[ks][fm], acc[fo][fm], 0, 0, 0);
        __builtin_amdgcn_s_setprio(0);
        // P2
        #pragma unroll
        for (int fm = 0; fm < 2; ++fm) {
            bfh[0][fm] = *(const short8*)(lXc + boff[1][fm] + octA);
            bfh[1][fm] = *(const short8*)(lXc + boff[1][fm] + octB);
        }
        __builtin_amdgcn_s_setprio(1);
        #pragma unroll
        for (int ks = 0; ks < 2; ++ks)
            #pragma unroll
            for (int fo = 0; fo < 3; ++fo)
                #pragma unroll
                for (int fm = 0; fm < 2; ++fm)
                    acc[fo][2 + fm] = __builtin_amdgcn_mfma_f32_16x16x32_bf16(
                        af[ks][fo], bfh[ks][fm], acc[fo][2 + fm], 0, 0, 0);
        __builtin_amdgcn_s_setprio(0);
        // P3
        #pragma unroll
        for (int fo = 0; fo < 3; ++fo) {
            af[0][fo] = *(const short8*)(lWc + aoff[1][fo] + octA);
            af[1][fo] = *(const short8*)(lWc + aoff[1][fo] + octB);
        }
        __builtin_amdgcn_s_setprio(1);
        #pragma unroll
        for (int ks = 0; ks < 2; ++ks)
            #pragma unroll
            for (int fo = 0; fo < 3; ++fo)
                #pragma unroll
                for (int fm = 0; fm < 2; ++fm)
                    acc[3 + fo][2 + fm] = __builtin_amdgcn_mfma_f32_16x16x32_bf16(
                        af[ks][fo], bfh[ks][fm], acc[3 + fo][2 + fm], 0, 0, 0);
        __builtin_amdgcn_s_setprio(0);
        // P4
        __builtin_amdgcn_s_setprio(1);
        #pragma unroll
        for (int ks = 0; ks < 2; ++ks)
            #pragma unroll
            for (int fo = 0; fo < 3; ++fo)
                #pragma unroll
                for (int fm = 0; fm < 2; ++fm)
                    acc[3 + fo][fm] = __builtin_amdgcn_mfma_f32_16x16x32_bf16(
                        af[ks][fo], bfl[ks][fm], acc[3 + fo][fm], 0, 0, 0);
        __builtin_amdgcn_s_setprio(0);
    }

    // ---- epilogue: D row = o (quad*4+reg), col = m (lane&15) -> coalesced along ow ----
    float alpha = ws[0];
    #pragma unroll
    for (int i = 0; i < 6; ++i) {
        int o0 = (i / 3) * 192 + io * 48 + (i % 3) * 16 + quad * 4;
        #pragma unroll
        for (int j = 0; j < 4; ++j) {
            int m = m_base + (j >> 1) * 64 + im * 32 + (j & 1) * 16 + l15;
            int nn = m >> 10, ohh = (m >> 5) & 31, oww = m & 31;
            #pragma unroll
            for (int r = 0; r < 4; ++r) {
                int o = o0 + r;
                out[((nn * 384 + o) * OHW + ohh) * OHW + oww] = alpha * acc[i][j][r] + bias[o];
            }
        }
    }
}

extern "C" void kernel_launch(void* const* d_in, const int* in_sizes, int n_in,
                              void* d_out, int out_size, void* d_ws, size_t ws_size,
                              hipStream_t stream) {
    (void)in_sizes; (void)n_in; (void)out_size; (void)ws_size;
    const float* x    = (const float*)d_in[0];
    const float* w    = (const float*)d_in[1];
    const float* bias = (const float*)d_in[2];
    float* out = (float*)d_out;
    float* wsf = (float*)d_ws;
    bf16* xn = (bf16*)((char*)d_ws + XN_OFF);
    bf16* wq = (bf16*)((char*)d_ws + WQ_OFF);
    const bf16* zg = (const bf16*)(wsf + ZG_F);

    absum_part<<<NPART, 256, 0, stream>>>(w, wsf);
    absum_final<<<1, 64, 0, stream>>>(wsf);
    quant_kernel<<<(NWELT + 255) / 256, 256, 0, stream>>>(w, wsf, wq);
    nhwc_kernel<<<dim3(2048, 6), 256, 0, stream>>>(x, xn);
    conv_gemm<<<dim3(MDIM / BM, 1), 512, 0, stream>>>(xn, wq, wsf, bias, out, zg);
}